// Round 5
// baseline (137.583 us; speedup 1.0000x reference)
//
#include <hip/hip_runtime.h>
#include <hip/hip_bf16.h>
#include <cstdint>

typedef __attribute__((ext_vector_type(8))) __bf16 bf8;
typedef __attribute__((ext_vector_type(4))) float f32x4;

// order-preserving float<->uint maps (for atomicMin/Max on sim values)
__device__ __forceinline__ unsigned mapf(float x){
  unsigned u = __float_as_uint(x);
  return (u & 0x80000000u) ? ~u : (u | 0x80000000u);
}
__device__ __forceinline__ float unmapf(unsigned u){
  return __uint_as_float((u & 0x80000000u) ? (u & 0x7FFFFFFFu) : ~u);
}

__device__ float digammaf_(float x){
  float r = 0.f;
  while (x < 6.f){ r -= 1.f/x; x += 1.f; }
  float inv = 1.f/x, inv2 = inv*inv;
  r += logf(x) - 0.5f*inv
     - inv2*(0.08333333333f - inv2*(0.008333333333f - inv2*0.003968253968f));
  return r;
}

// ============ k_prep: normalize -> fragment-ordered bf16 (fb2) + losses =====
// fb2 layout (MFMA-fragment, LANE order): panel p=row/64 (NCH chunks), chunk
// cc=k/32, sub-block mi=(row%64)/16; within a 512-elem block, element
// (r16=row%16, q=(k%32)/8, j=k%8) lives at (q*16 + r16)*8 + j.
// => k_pairs lane L reads bytes [L*16, L*16+16) of the block: quarter-wave =
// 4 contiguous 64B lines (ideal VMEM coalescing).
__global__ __launch_bounds__(256) void k_prep(const float* __restrict__ feat,
    __bf16* __restrict__ fb2,
    const float* __restrict__ logits, const int* __restrict__ targets,
    const float* __restrict__ alpha,  const float* __restrict__ fa,
    const float* __restrict__ cw, int B, int D,
    float* __restrict__ psum, unsigned* rowMinU, unsigned* rowMaxU){
  int bid = blockIdx.x, tid = threadIdx.x;
  int wave = tid >> 6, lane = tid & 63;

  int row = bid*4 + wave;                       // grid = B/4, always < B
  // ---- normalize one row per wave ----
  const float* src = feat + (size_t)row*D;
  float ss = 0.f;
  for (int c = lane*4; c < D; c += 64*4){
    float4 v = *(const float4*)(src + c);
    ss += v.x*v.x + v.y*v.y + v.z*v.z + v.w*v.w;
  }
  #pragma unroll
  for (int off=32; off; off>>=1) ss += __shfl_xor(ss, off);
  float inv = 1.f / fmaxf(sqrtf(ss), 1e-12f);

  int p = row >> 6, r = row & 63;
  int mi = r >> 4, l16r = r & 15;
  int NCH = D >> 5;
  for (int c = lane*8; c < D; c += 64*8){
    float4 v0 = *(const float4*)(src + c);
    float4 v1 = *(const float4*)(src + c + 4);
    bf8 o;
    o[0]=(__bf16)(v0.x*inv); o[1]=(__bf16)(v0.y*inv);
    o[2]=(__bf16)(v0.z*inv); o[3]=(__bf16)(v0.w*inv);
    o[4]=(__bf16)(v1.x*inv); o[5]=(__bf16)(v1.y*inv);
    o[6]=(__bf16)(v1.z*inv); o[7]=(__bf16)(v1.w*inv);
    int cc = c >> 5;                  // chunk
    int q  = (c >> 3) & 3;            // 8-elem kgroup within chunk
    size_t off = ((size_t)(p*NCH + cc)*4 + mi)*512 + (q*16 + l16r)*8;
    *(bf8*)(fb2 + off) = o;
  }

  // ---- init row min/max (4 rows per block) ----
  if (tid < 4){ rowMinU[bid*4+tid] = 0xFFFFFFFFu; rowMaxU[bid*4+tid] = 0u; }

  // ---- per-sample losses: wave 0 only, lanes 0..3 take the 4 samples ----
  if (wave == 0){
    float r0=0.f,r1=0.f,r2=0.f,r3=0.f,r4=0.f,r5=0.f;
    if (lane < 4){
      int i = bid*4 + lane;
      float l0=logits[3*i], l1=logits[3*i+1], l2=logits[3*i+2];
      int t = targets[i];
      float m = fmaxf(l0, fmaxf(l1,l2));
      float e0=expf(l0-m), e1=expf(l1-m), e2=expf(l2-m);
      float se = e0+e1+e2;
      float lse = m + logf(se);
      float lp0=l0-lse, lp1=l1-lse, lp2=l2-lse;
      float lpt = (t==0)?lp0:((t==1)?lp1:lp2);
      float nll = -lpt;
      float ce_ls = 0.9f*nll + 0.1f*(-(lp0+lp1+lp2)*(1.f/3.f));
      float pt = expf(-ce_ls);
      float om = 1.f - pt;
      float focal_i = fa[t]*om*om*ce_ls;
      float w = cw[t];
      float ce_n = w*nll, ce_d = w;
      float p0=e0/se, p1=e1/se, p2=e2/se;
      float bnd;
      if (t==0)      bnd = p1 + 0.6f*p2;
      else if (t==2) bnd = p1 + 0.4f*p0;
      else           bnd = 4.5f*(1.f - p1 + 0.3f*(p0+p2));
      float a0=alpha[3*i], a1=alpha[3*i+1], a2=alpha[3*i+2];
      float S = a0+a1+a2 + 1e-8f;
      float at_ = (t==0)?a0:((t==1)?a1:a2);
      float lik = digammaf_(S) - digammaf_(at_ + 1e-8f);
      float b0 = (t==0)?1.f:a0, b1 = (t==1)?1.f:a1, b2 = (t==2)?1.f:a2;
      float ats = b0+b1+b2 + 1e-8f;
      float psa = digammaf_(ats + 1e-8f);
      float kl = lgammaf(ats)
         - (lgammaf(b0+1e-8f)+lgammaf(b1+1e-8f)+lgammaf(b2+1e-8f))
         + (b0-1.f)*(digammaf_(b0+1e-8f)-psa)
         + (b1-1.f)*(digammaf_(b1+1e-8f)-psa)
         + (b2-1.f)*(digammaf_(b2+1e-8f)-psa);
      r0=focal_i; r1=ce_n; r2=ce_d; r3=bnd; r4=lik; r5=kl;
    }
    float s0 = ((__shfl(r0,0)+__shfl(r0,1))+__shfl(r0,2))+__shfl(r0,3);
    float s1 = ((__shfl(r1,0)+__shfl(r1,1))+__shfl(r1,2))+__shfl(r1,3);
    float s2 = ((__shfl(r2,0)+__shfl(r2,1))+__shfl(r2,2))+__shfl(r2,3);
    float s3 = ((__shfl(r3,0)+__shfl(r3,1))+__shfl(r3,2))+__shfl(r3,3);
    float s4 = ((__shfl(r4,0)+__shfl(r4,1))+__shfl(r4,2))+__shfl(r4,3);
    float s5 = ((__shfl(r5,0)+__shfl(r5,1))+__shfl(r5,2))+__shfl(r5,3);
    if (lane == 0){
      psum[bid*8+0]=s0; psum[bid*8+1]=s1; psum[bid*8+2]=s2;
      psum[bid*8+3]=s3; psum[bid*8+4]=s4; psum[bid*8+5]=s5;
    }
  }
}

// ============ k_pairs: 256-thread blocks, 4 independent pair-waves =========
// Round-4 post-mortem: single-wave workgroups cap at ~6 WG/CU (Occupancy
// pinned ~20% across 2080- and 8192-block grids) -> latency-bound at 23% of
// L2 BW. Fix: pack 4 pair-waves per 256-thread workgroup (no LDS/barriers);
// WG-slot limit now gives ~32 waves/CU. Per-wave logic identical to the
// validated round-2/3 version (2-deep rotation) => absmax 0.
__global__ __launch_bounds__(256) void k_pairs(const __bf16* __restrict__ fb2,
    const int* __restrict__ targets, int B, int D, int nslot,
    float* __restrict__ pairPart, unsigned* rowMinU, unsigned* rowMaxU){
  int NBY = B >> 5;                 // number of 32-row groups
  int wave = threadIdx.x >> 6, lane = threadIdx.x & 63;
  int slot = blockIdx.x*4 + wave;
  if (slot >= nslot) return;
  int by  = slot % NBY;
  int p   = slot / NBY;
  int bx0 = by + 2*p;
  if (bx0 >= NBY){                  // inactive pair slot: zero its partials
    if (lane == 0) *(float4*)(pairPart + slot*4) = make_float4(0.f,0.f,0.f,0.f);
    return;
  }
  int bx1 = bx0 + 1;
  bool hasT1 = (bx1 < NBY);
  bool isDiag0 = (bx0 == by);
  int rowBase = by*32, colBase0 = bx0*32, colBase1 = bx1*32;

  int quad = lane >> 4, l16 = lane & 15;
  int NCH = D >> 5;

  const __bf16* pA  = fb2 + ((size_t)(by >>1)*NCH*4 + (by &1)*2)*512 + lane*8;
  const __bf16* pB0 = fb2 + ((size_t)(bx0>>1)*NCH*4 + (bx0&1)*2)*512 + lane*8;
  const __bf16* pB1 = hasT1
      ? fb2 + ((size_t)(bx1>>1)*NCH*4 + (bx1&1)*2)*512 + lane*8
      : pB0;                        // harmless duplicate loads; epi skipped

  // hoist targets loads: latency hides under the K loop
  int trow = targets[rowBase + (lane & 31)];   // lane rl holds targets[rowBase+rl]
  int tcol0[2], tcol1[2];
  tcol0[0] = targets[colBase0 + l16];
  tcol0[1] = targets[colBase0 + 16 + l16];
  tcol1[0] = hasT1 ? targets[colBase1 + l16]      : 0;
  tcol1[1] = hasT1 ? targets[colBase1 + 16 + l16] : 0;

  f32x4 C0[2][2] = {};
  f32x4 C1[2][2] = {};

  #define LD(Ab, B0b, B1b, it) do{ \
    Ab[0]  = *(const bf8*)(pA  + (size_t)(it)*2048); \
    Ab[1]  = *(const bf8*)(pA  + (size_t)(it)*2048 + 512); \
    B0b[0] = *(const bf8*)(pB0 + (size_t)(it)*2048); \
    B0b[1] = *(const bf8*)(pB0 + (size_t)(it)*2048 + 512); \
    B1b[0] = *(const bf8*)(pB1 + (size_t)(it)*2048); \
    B1b[1] = *(const bf8*)(pB1 + (size_t)(it)*2048 + 512); \
  }while(0)

  #define COMP(Ab, B0b, B1b) do{ \
    _Pragma("unroll") \
    for (int mi=0; mi<2; mi++) \
      _Pragma("unroll") \
      for (int ni=0; ni<2; ni++) \
        C0[mi][ni] = __builtin_amdgcn_mfma_f32_16x16x32_bf16(Ab[mi], B0b[ni], C0[mi][ni], 0,0,0); \
    _Pragma("unroll") \
    for (int mi=0; mi<2; mi++) \
      _Pragma("unroll") \
      for (int ni=0; ni<2; ni++) \
        C1[mi][ni] = __builtin_amdgcn_mfma_f32_16x16x32_bf16(Ab[mi], B1b[ni], C1[mi][ni], 0,0,0); \
  }while(0)

  {
    bf8 A0[2], B00[2], B10[2], A1[2], B01[2], B11[2];
    LD(A0, B00, B10, 0);
    for (int it=0; it<NCH; it+=2){
      LD(A1, B01, B11, it+1);
      COMP(A0, B00, B10);
      if (it+2 < NCH) LD(A0, B00, B10, it+2);
      COMP(A1, B01, B11);
    }
  }
  #undef LD
  #undef COMP

  // ---- fused epilogue ----
  float rowMinReg = 2.f, rowMaxReg = -2.f;     // slot regs (lanes l16<8)
  float posA=0.f, negA=0.f, semiA=0.f, diagA=0.f;
  float posB=0.f, negB=0.f, semiB=0.f, diagB=0.f;

  auto epi = [&](const f32x4 (&Cx)[2][2], const int (&tcolx)[2], int colBasex,
                 bool isD, float& posx, float& negx, float& semix, float& diagx){
    float cmin[2] = {2.f, 2.f}, cmax[2] = {-2.f, -2.f};
    #pragma unroll
    for (int mi=0; mi<2; mi++){
      #pragma unroll
      for (int r=0; r<4; r++){
        int rl = mi*16 + quad*4 + r;
        int row = rowBase + rl;
        int tr = __shfl(trow, rl);
        float vmin = 2.f, vmax = -2.f;
        #pragma unroll
        for (int ni=0; ni<2; ni++){
          int col = colBasex + ni*16 + l16;
          float s = Cx[mi][ni][r];
          if (tr == tcolx[ni]){
            float omv = 1.f - s;
            float q = omv*omv;
            posx += q;
            if (tr == 1) semix += q;
            if (row == col) diagx += q;      // only on the diagonal tile
            else {
              vmin = fminf(vmin, s);
              cmin[ni] = fminf(cmin[ni], s);
            }
          } else {
            float c0 = fmaxf(s - 0.2f, 0.f);
            negx += c0*c0;
            vmax = fmaxf(vmax, s);
            cmax[ni] = fmaxf(cmax[ni], s);
          }
        }
        #pragma unroll
        for (int off=1; off<16; off<<=1){
          vmin = fminf(vmin, __shfl_xor(vmin, off));
          vmax = fmaxf(vmax, __shfl_xor(vmax, off));
        }
        if (l16 == mi*4 + r){                // keep into per-lane row slot
          rowMinReg = fminf(rowMinReg, vmin);
          rowMaxReg = fmaxf(rowMaxReg, vmax);
        }
      }
    }
    if (!isD){                               // col contribution (off-diag only)
      #pragma unroll
      for (int ni=0; ni<2; ni++){
        cmin[ni] = fminf(cmin[ni], __shfl_xor(cmin[ni], 16));
        cmin[ni] = fminf(cmin[ni], __shfl_xor(cmin[ni], 32));
        cmax[ni] = fmaxf(cmax[ni], __shfl_xor(cmax[ni], 16));
        cmax[ni] = fmaxf(cmax[ni], __shfl_xor(cmax[ni], 32));
      }
      if (lane < 32){                        // one instr, 32 lanes: col = base+lane
        float cnv = (lane < 16) ? cmin[0] : cmin[1];
        float cxv = (lane < 16) ? cmax[0] : cmax[1];
        atomicMin(&rowMinU[colBasex + lane], mapf(cnv));
        atomicMax(&rowMaxU[colBasex + lane], mapf(cxv));
      }
    }
  };

  epi(C0, tcol0, colBase0, isDiag0, posA, negA, semiA, diagA);
  if (hasT1) epi(C1, tcol1, colBase1, false, posB, negB, semiB, diagB);

  // one batched row-atomic pair for BOTH tiles (32 active lanes)
  if (l16 < 8){
    int row = rowBase + quad*4 + (l16 & 3) + 16*(l16 >> 2);
    atomicMin(&rowMinU[row], mapf(rowMinReg));
    atomicMax(&rowMaxU[row], mapf(rowMaxReg));
  }

  float fac0 = isDiag0 ? 1.f : 2.f;          // x2 is exact in fp
  float pos  = posA*fac0 + posB*2.f;
  float neg  = negA*fac0 + negB*2.f;
  float semi = semiA*fac0 + semiB*2.f;
  float diag = diagA;

  #pragma unroll
  for (int off=32; off; off>>=1){
    pos  += __shfl_xor(pos, off);
    neg  += __shfl_xor(neg, off);
    semi += __shfl_xor(semi, off);
    diag += __shfl_xor(diag, off);
  }
  if (lane == 0)
    *(float4*)(pairPart + slot*4) = make_float4(pos, neg, semi, diag);
}

// ============ k_final: 1024 threads; histogram + reductions + combine ======
__global__ __launch_bounds__(1024) void k_final(const int* __restrict__ targets,
    const int* __restrict__ epoch_p, int B, int nprep, int nblk,
    const float* __restrict__ pairPart, const float* __restrict__ psum,
    const unsigned* rowMinU, const unsigned* rowMaxU, float* out){
  int tid = threadIdx.x, wave = tid>>6, lane = tid&63;
  __shared__ float redf[16][8];
  __shared__ int   redi[16][4];
  __shared__ float tot6[6];
  __shared__ int   cns[3];
  __shared__ float ptot[4];

  // ---- 1) histogram targets (int4 loads) ----
  {
    int c0=0,c1=0,c2=0;
    for (int i4 = tid; i4 < B/4; i4 += 1024){
      int4 tv = ((const int4*)targets)[i4];
      c0 += (tv.x==0)+(tv.y==0)+(tv.z==0)+(tv.w==0);
      c1 += (tv.x==1)+(tv.y==1)+(tv.z==1)+(tv.w==1);
      c2 += (tv.x==2)+(tv.y==2)+(tv.z==2)+(tv.w==2);
    }
    #pragma unroll
    for (int off=32; off; off>>=1){
      c0+=__shfl_xor(c0,off); c1+=__shfl_xor(c1,off); c2+=__shfl_xor(c2,off);
    }
    if (lane==0){ redi[wave][0]=c0; redi[wave][1]=c1; redi[wave][2]=c2; }
  }
  // ---- 2) per-sample partials ----
  {
    float v0=0,v1=0,v2=0,v3=0,v4=0,v5=0;
    for (int s = tid; s < nprep; s += 1024){
      float4 a = *(const float4*)(psum + s*8);
      float4 b = *(const float4*)(psum + s*8 + 4);
      v0+=a.x; v1+=a.y; v2+=a.z; v3+=a.w; v4+=b.x; v5+=b.y;
    }
    #pragma unroll
    for (int off=32; off; off>>=1){
      v0+=__shfl_xor(v0,off); v1+=__shfl_xor(v1,off); v2+=__shfl_xor(v2,off);
      v3+=__shfl_xor(v3,off); v4+=__shfl_xor(v4,off); v5+=__shfl_xor(v5,off);
    }
    if (lane==0){
      redf[wave][0]=v0; redf[wave][1]=v1; redf[wave][2]=v2;
      redf[wave][3]=v3; redf[wave][4]=v4; redf[wave][5]=v5;
    }
  }
  __syncthreads();
  if (tid == 0){
    int c0=0,c1=0,c2=0;
    float v[6]={0,0,0,0,0,0};
    for (int w2=0; w2<16; w2++){
      c0+=redi[w2][0]; c1+=redi[w2][1]; c2+=redi[w2][2];
      for (int j=0;j<6;j++) v[j]+=redf[w2][j];
    }
    cns[0]=c0; cns[1]=c1; cns[2]=c2;
    for (int j=0;j<6;j++) tot6[j]=v[j];
  }
  __syncthreads();

  // ---- 3) pair partials ----
  {
    float p=0,n=0,s2=0,d=0;
    for (int s = tid; s < nblk; s += 1024){
      float4 a = *(const float4*)(pairPart + s*4);
      p+=a.x; n+=a.y; s2+=a.z; d+=a.w;
    }
    #pragma unroll
    for (int off=32; off; off>>=1){
      p+=__shfl_xor(p,off); n+=__shfl_xor(n,off);
      s2+=__shfl_xor(s2,off); d+=__shfl_xor(d,off);
    }
    if (lane==0){ redf[wave][0]=p; redf[wave][1]=n; redf[wave][2]=s2; redf[wave][3]=d; }
  }
  __syncthreads();
  if (tid == 0){
    float a=0,b=0,c=0,e=0;
    for (int w2=0; w2<16; w2++){ a+=redf[w2][0]; b+=redf[w2][1]; c+=redf[w2][2]; e+=redf[w2][3]; }
    ptot[0]=a; ptot[1]=b; ptot[2]=c; ptot[3]=e;
  }
  __syncthreads();

  int n0=cns[0], n1=cns[1], n2=cns[2];

  // ---- 4) triplet ----
  float tsum = 0.f, tcnt = 0.f;
  for (int i = tid; i < B; i += 1024){
    int t = targets[i];
    int nt = (t==0)?n0:((t==1)?n1:n2);
    if (nt - 1 > 0 && B - nt > 0){
      float mn = unmapf(rowMinU[i]);
      float mx = unmapf(rowMaxU[i]);
      float hp = sqrtf(fmaxf(2.f - 2.f*mn, 0.f));
      float hn = sqrtf(fmaxf(2.f - 2.f*mx, 0.f));
      float margin = 1.5f * ((t==1) ? 2.5f : 1.f);
      float tl = fmaxf(hp - hn + margin, 0.f);
      tsum += tl; tcnt += 1.f;
    }
  }
  #pragma unroll
  for (int off=32; off; off>>=1){ tsum += __shfl_xor(tsum, off); tcnt += __shfl_xor(tcnt, off); }
  if (lane==0){ redf[wave][6]=tsum; redf[wave][7]=tcnt; }
  __syncthreads();

  if (tid==0){
    float ts=0, tn=0;
    for (int w2=0; w2<16; w2++){ ts+=redf[w2][6]; tn+=redf[w2][7]; }
    float triplet = (tn > 0.f) ? ts / fmaxf(tn, 1.f) : 0.f;
    float pos=ptot[0], neg=ptot[1], semi=ptot[2], diag=ptot[3];
    float Bf = (float)B;
    float focal = tot6[0] / Bf;
    float ce = tot6[1] / tot6[2];
    float boundary = tot6[3] / (Bf + 1e-8f);
    float contrastive = (pos + neg + 4.f*semi) / (Bf*Bf + 1e-8f);
    long long npl = ((long long)n0*(n0-1) + (long long)n1*(n1-1) + (long long)n2*(n2-1))/2;
    float qsum = (pos - diag) * 0.5f;
    float q = qsum / (float)(npl > 0 ? npl : 1);
    if (n2 > 0) q *= (1.f + 2.5f * ((float)n2 / Bf));
    float quality = (npl > 0) ? q : 0.f;
    int ep = epoch_p[0];
    float er = (float)ep / 25.f;
    float ann = fminf(1.f, er*er);
    float evidential = tot6[4]/Bf + ann*0.2f*tot6[5]/Bf;
    float total = 0.4f*focal + 0.3f*ce + 0.15f*boundary
                + 0.1f*contrastive + 0.1f*triplet + 0.1f*quality + 0.1f*evidential;
    out[0] = total;
  }
}

extern "C" void kernel_launch(void* const* d_in, const int* in_sizes, int n_in,
                              void* d_out, int out_size, void* d_ws, size_t ws_size,
                              hipStream_t stream){
  const float* logits   = (const float*)d_in[0];
  const int*   targets  = (const int*)d_in[1];
  const float* features = (const float*)d_in[2];
  const float* alpha    = (const float*)d_in[3];
  const int*   epoch    = (const int*)d_in[4];
  const float* fa       = (const float*)d_in[5];
  const float* cw       = (const float*)d_in[6];
  int B = in_sizes[1];
  int D = in_sizes[2] / B;
  int nprep = B/4;                 // k_prep blocks == psum slots
  int NBY = B / 32;                // 32-row groups
  int PMAX = (NBY + 1) / 2;        // max tile-pairs per row group
  int nslot = NBY * PMAX;          // pair slots (8192 @ B=4096)
  int nblk4 = (nslot + 3) / 4;     // 256-thread blocks, 4 pair-waves each

  char* ws = (char*)d_ws;
  float*    psum     = (float*)(ws);                          // nprep*8 f32 (32KB)
  float*    pairPart = (float*)(ws + 65536);                  // nslot*4 f32 (128KB)
  unsigned* rowMinU  = (unsigned*)(ws + 65536 + 196608);      // B u32
  unsigned* rowMaxU  = (unsigned*)(ws + 65536 + 196608 + (size_t)B*4);
  __bf16*   fb2      = (__bf16*)(ws + 65536 + 196608 + (size_t)B*8);  // B*D bf16

  k_prep <<<nprep, 256, 0, stream>>>(features, fb2, logits, targets, alpha, fa, cw,
                                     B, D, psum, rowMinU, rowMaxU);
  k_pairs<<<nblk4, 256, 0, stream>>>(fb2, targets, B, D, nslot, pairPart,
                                     rowMinU, rowMaxU);
  k_final<<<1, 1024, 0, stream>>>(targets, epoch, B, nprep, nslot, pairPart, psum,
                                  rowMinU, rowMaxU, (float*)d_out);
}

// Round 7
// 123.308 us; speedup vs baseline: 1.1158x; 1.1158x over previous
//
#include <hip/hip_runtime.h>
#include <hip/hip_bf16.h>
#include <cstdint>

typedef __attribute__((ext_vector_type(8))) __bf16 bf8;
typedef __attribute__((ext_vector_type(4))) float f32x4;

#if defined(__has_builtin)
#if __has_builtin(__builtin_amdgcn_global_load_lds)
#define USE_GLL 1
#endif
#endif
#ifndef USE_GLL
#define USE_GLL 0
#endif

#if USE_GLL
// global src is a PER-LANE address; LDS dst is wave-uniform base,
// HW deposits lane i at dst + i*16B.
__device__ __forceinline__ void gll16(const __bf16* g, __bf16* l){
  __builtin_amdgcn_global_load_lds(
      (const __attribute__((address_space(1))) void*)g,
      (__attribute__((address_space(3))) void*)l, 16, 0, 0);
}
#endif

// order-preserving float<->uint maps (for atomicMin/Max on sim values)
__device__ __forceinline__ unsigned mapf(float x){
  unsigned u = __float_as_uint(x);
  return (u & 0x80000000u) ? ~u : (u | 0x80000000u);
}
__device__ __forceinline__ float unmapf(unsigned u){
  return __uint_as_float((u & 0x80000000u) ? (u & 0x7FFFFFFFu) : ~u);
}

__device__ float digammaf_(float x){
  float r = 0.f;
  while (x < 6.f){ r -= 1.f/x; x += 1.f; }
  float inv = 1.f/x, inv2 = inv*inv;
  r += logf(x) - 0.5f*inv
     - inv2*(0.08333333333f - inv2*(0.008333333333f - inv2*0.003968253968f));
  return r;
}

// ============ k_prep: normalize -> TILED bf16 (fb2) + per-sample losses =====
// fb2 layout (round-0, validated): panel p=row/64 (64 rows), chunk c=k/32;
// each chunk is 4KB CONTIGUOUS: elem (r=row%64, kk=k%32) at
// (p*NCH+c)*2048 + r*32 + cb'*8 + kk%8, cb' = (kk/8) ^ ((r>>1)&3).
__global__ __launch_bounds__(256) void k_prep(const float* __restrict__ feat,
    __bf16* __restrict__ fb2,
    const float* __restrict__ logits, const int* __restrict__ targets,
    const float* __restrict__ alpha,  const float* __restrict__ fa,
    const float* __restrict__ cw, int B, int D,
    float* __restrict__ psum, unsigned* rowMinU, unsigned* rowMaxU){
  int bid = blockIdx.x, tid = threadIdx.x;
  int wave = tid >> 6, lane = tid & 63;

  int row = bid*4 + wave;                       // grid = B/4, always < B
  // ---- normalize one row per wave ----
  const float* src = feat + (size_t)row*D;
  float ss = 0.f;
  for (int c = lane*4; c < D; c += 64*4){
    float4 v = *(const float4*)(src + c);
    ss += v.x*v.x + v.y*v.y + v.z*v.z + v.w*v.w;
  }
  #pragma unroll
  for (int off=32; off; off>>=1) ss += __shfl_xor(ss, off);
  float inv = 1.f / fmaxf(sqrtf(ss), 1e-12f);

  int p = row >> 6, r = row & 63;
  int rsw = (r >> 1) & 3;
  int NCH = D >> 5;
  for (int c = lane*8; c < D; c += 64*8){
    float4 v0 = *(const float4*)(src + c);
    float4 v1 = *(const float4*)(src + c + 4);
    bf8 o;
    o[0]=(__bf16)(v0.x*inv); o[1]=(__bf16)(v0.y*inv);
    o[2]=(__bf16)(v0.z*inv); o[3]=(__bf16)(v0.w*inv);
    o[4]=(__bf16)(v1.x*inv); o[5]=(__bf16)(v1.y*inv);
    o[6]=(__bf16)(v1.z*inv); o[7]=(__bf16)(v1.w*inv);
    int cc = c >> 5;                  // chunk
    int cb = (c >> 3) & 3;            // 8-elem group within chunk
    size_t off = (size_t)(p*NCH + cc)*2048 + r*32 + ((cb ^ rsw)*8);
    *(bf8*)(fb2 + off) = o;
  }

  // ---- init row min/max (4 rows per block) ----
  if (tid < 4){ rowMinU[bid*4+tid] = 0xFFFFFFFFu; rowMaxU[bid*4+tid] = 0u; }

  // ---- per-sample losses: wave 0 only, lanes 0..3 take the 4 samples ----
  // (validated rounds 1-5; psum bit-identical to round-0's redundant version)
  if (wave == 0){
    float r0=0.f,r1=0.f,r2=0.f,r3=0.f,r4=0.f,r5=0.f;
    if (lane < 4){
      int i = bid*4 + lane;
      float l0=logits[3*i], l1=logits[3*i+1], l2=logits[3*i+2];
      int t = targets[i];
      float m = fmaxf(l0, fmaxf(l1,l2));
      float e0=expf(l0-m), e1=expf(l1-m), e2=expf(l2-m);
      float se = e0+e1+e2;
      float lse = m + logf(se);
      float lp0=l0-lse, lp1=l1-lse, lp2=l2-lse;
      float lpt = (t==0)?lp0:((t==1)?lp1:lp2);
      float nll = -lpt;
      float ce_ls = 0.9f*nll + 0.1f*(-(lp0+lp1+lp2)*(1.f/3.f));
      float pt = expf(-ce_ls);
      float om = 1.f - pt;
      float focal_i = fa[t]*om*om*ce_ls;
      float w = cw[t];
      float ce_n = w*nll, ce_d = w;
      float p0=e0/se, p1=e1/se, p2=e2/se;
      float bnd;
      if (t==0)      bnd = p1 + 0.6f*p2;
      else if (t==2) bnd = p1 + 0.4f*p0;
      else           bnd = 4.5f*(1.f - p1 + 0.3f*(p0+p2));
      float a0=alpha[3*i], a1=alpha[3*i+1], a2=alpha[3*i+2];
      float S = a0+a1+a2 + 1e-8f;
      float at_ = (t==0)?a0:((t==1)?a1:a2);
      float lik = digammaf_(S) - digammaf_(at_ + 1e-8f);
      float b0 = (t==0)?1.f:a0, b1 = (t==1)?1.f:a1, b2 = (t==2)?1.f:a2;
      float ats = b0+b1+b2 + 1e-8f;
      float psa = digammaf_(ats + 1e-8f);
      float kl = lgammaf(ats)
         - (lgammaf(b0+1e-8f)+lgammaf(b1+1e-8f)+lgammaf(b2+1e-8f))
         + (b0-1.f)*(digammaf_(b0+1e-8f)-psa)
         + (b1-1.f)*(digammaf_(b1+1e-8f)-psa)
         + (b2-1.f)*(digammaf_(b2+1e-8f)-psa);
      r0=focal_i; r1=ce_n; r2=ce_d; r3=bnd; r4=lik; r5=kl;
    }
    float s0 = ((__shfl(r0,0)+__shfl(r0,1))+__shfl(r0,2))+__shfl(r0,3);
    float s1 = ((__shfl(r1,0)+__shfl(r1,1))+__shfl(r1,2))+__shfl(r1,3);
    float s2 = ((__shfl(r2,0)+__shfl(r2,1))+__shfl(r2,2))+__shfl(r2,3);
    float s3 = ((__shfl(r3,0)+__shfl(r3,1))+__shfl(r3,2))+__shfl(r3,3);
    float s4 = ((__shfl(r4,0)+__shfl(r4,1))+__shfl(r4,2))+__shfl(r4,3);
    float s5 = ((__shfl(r5,0)+__shfl(r5,1))+__shfl(r5,2))+__shfl(r5,3);
    if (lane == 0){
      psum[bid*8+0]=s0; psum[bid*8+1]=s1; psum[bid*8+2]=s2;
      psum[bid*8+3]=s3; psum[bid*8+4]=s4; psum[bid*8+5]=s5;
    }
  }
}

// ============ k_pairs: round-0 structure VERBATIM + XCD tile swizzle only ===
// Round-6 post-mortem: 3-deep gll16 rotation raced (NaN) — the implicit
// compiler-inserted vmcnt is only validated for THIS exact 2-buffer shape.
// Only change vs round 0: bijective XCD-chunked remap blockIdx->t (m204)
// so each XCD's private L2 keeps a contiguous band of panels; pairPart
// indexed by t (k_final's sum is permutation-tolerant).
__global__ __launch_bounds__(64) void k_pairs(const __bf16* __restrict__ fb2,
    const int* __restrict__ targets, int B, int D, int nblk,
    float* __restrict__ pairPart, unsigned* rowMinU, unsigned* rowMaxU){
  __shared__ __bf16 sA[2][2048];
  __shared__ __bf16 sB[2][2048];

  // XCD-chunked bijective remap (m204): raw -> tile id t
  int raw = blockIdx.x;
  int q8 = nblk >> 3, r8 = nblk & 7;
  int xcd = raw & 7, o8 = raw >> 3;
  int t = (xcd < r8 ? xcd*(q8+1) : r8*(q8+1) + (xcd-r8)*q8) + o8;

  // decode triangular tile index -> (by, bx), by <= bx
  int bx = (int)((sqrtf(8.f*(float)t + 1.f) - 1.f)*0.5f);
  while ((bx+1)*(bx+2)/2 <= t) bx++;
  while (bx*(bx+1)/2 > t) bx--;
  int by = t - bx*(bx+1)/2;
  bool isDiag = (by == bx);
  int rowBase = by*64, colBase = bx*64;

  int lane = threadIdx.x;
  int quad = lane >> 4, l16 = lane & 15;
  int NCH = D/32;                                   // 16 chunks per panel

  const __bf16* srcA = fb2 + (size_t)by*NCH*2048 + lane*8;  // per-lane 16B
  const __bf16* srcB = fb2 + (size_t)bx*NCH*2048 + lane*8;
  const __bf16* sB0  = isDiag ? &sA[0][0] : &sB[0][0];

  // fragment LDS offsets (elements), inverse swizzle; A and B identical form
  int offA[4];
  #pragma unroll
  for (int mi=0; mi<4; mi++){
    int R = mi*16 + l16;
    offA[mi] = R*32 + ((quad ^ ((R>>1)&3))*8);
  }

  f32x4 C[4][4] = {};

#if USE_GLL
  #define STAGE(buf, it) do{ \
    const __bf16* ga_ = srcA + (it)*2048; \
    gll16(ga_ + 0*512, &sA[buf][0*512]); \
    gll16(ga_ + 1*512, &sA[buf][1*512]); \
    gll16(ga_ + 2*512, &sA[buf][2*512]); \
    gll16(ga_ + 3*512, &sA[buf][3*512]); \
    if (!isDiag){ \
      const __bf16* gb_ = srcB + (it)*2048; \
      gll16(gb_ + 0*512, &sB[buf][0*512]); \
      gll16(gb_ + 1*512, &sB[buf][1*512]); \
      gll16(gb_ + 2*512, &sB[buf][2*512]); \
      gll16(gb_ + 3*512, &sB[buf][3*512]); \
    } \
  }while(0)
#else
  #define STAGE(buf, it) do{ \
    const __bf16* ga_ = srcA + (it)*2048; \
    _Pragma("unroll") \
    for (int j=0; j<4; j++) \
      *(bf8*)&sA[buf][j*512 + lane*8] = *(const bf8*)(ga_ + j*512); \
    if (!isDiag){ \
      const __bf16* gb_ = srcB + (it)*2048; \
      _Pragma("unroll") \
      for (int j=0; j<4; j++) \
        *(bf8*)&sB[buf][j*512 + lane*8] = *(const bf8*)(gb_ + j*512); \
    } \
  }while(0)
#endif

  #define COMPUTE(buf) do{ \
    bf8 aF[4], bF[4]; \
    _Pragma("unroll") \
    for (int mi=0; mi<4; mi++) aF[mi] = *(const bf8*)(&sA[0][0] + (buf)*2048 + offA[mi]); \
    _Pragma("unroll") \
    for (int ni=0; ni<4; ni++) bF[ni] = *(const bf8*)(sB0 + (buf)*2048 + offA[ni]); \
    _Pragma("unroll") \
    for (int mi=0; mi<4; mi++) \
      _Pragma("unroll") \
      for (int ni=0; ni<4; ni++) \
        C[mi][ni] = __builtin_amdgcn_mfma_f32_16x16x32_bf16(aF[mi], bF[ni], C[mi][ni], 0,0,0); \
  }while(0)

  STAGE(0, 0);
  for (int it=0; it<NCH; it+=2){
    STAGE(1, it+1);
    COMPUTE(0);
    if (it+2 < NCH) STAGE(0, it+2);
    COMPUTE(1);
  }
  #undef STAGE
  #undef COMPUTE

  // ---- fused epilogue (round-0 verbatim, validated absmax 0) ----
  int tcol[4];
  #pragma unroll
  for (int ni=0; ni<4; ni++) tcol[ni] = targets[colBase + ni*16 + l16];

  float pos=0.f, neg=0.f, semi=0.f, diag=0.f;
  float cmin[4], cmax[4];
  #pragma unroll
  for (int ni=0; ni<4; ni++){ cmin[ni]=2.f; cmax[ni]=-2.f; }

  #pragma unroll
  for (int mi=0; mi<4; mi++){
    #pragma unroll
    for (int r=0; r<4; r++){
      int rl = mi*16 + quad*4 + r;
      int row = rowBase + rl;
      int tr = targets[row];
      float vmin = 2.f, vmax = -2.f;
      #pragma unroll
      for (int ni=0; ni<4; ni++){
        int col = colBase + ni*16 + l16;
        float s = C[mi][ni][r];
        if (tr == tcol[ni]){
          float omv = 1.f - s;
          float q = omv*omv;
          pos += q;
          if (tr == 1) semi += q;
          if (row == col) diag += q;     // only possible on diagonal tiles
          else {
            vmin = fminf(vmin, s);
            cmin[ni] = fminf(cmin[ni], s);
          }
        } else {
          float c0 = fmaxf(s - 0.2f, 0.f);
          neg += c0*c0;
          vmax = fmaxf(vmax, s);
          cmax[ni] = fmaxf(cmax[ni], s);
        }
      }
      #pragma unroll
      for (int off=1; off<16; off<<=1){
        vmin = fminf(vmin, __shfl_xor(vmin, off));
        vmax = fmaxf(vmax, __shfl_xor(vmax, off));
      }
      if (l16 == 0){
        atomicMin(&rowMinU[row], mapf(vmin));
        atomicMax(&rowMaxU[row], mapf(vmax));
      }
    }
  }

  if (!isDiag){
    #pragma unroll
    for (int ni=0; ni<4; ni++){
      float cn = cmin[ni], cx = cmax[ni];
      cn = fminf(cn, __shfl_xor(cn, 16)); cn = fminf(cn, __shfl_xor(cn, 32));
      cx = fmaxf(cx, __shfl_xor(cx, 16)); cx = fmaxf(cx, __shfl_xor(cx, 32));
      if (quad == 0){
        int col = colBase + ni*16 + l16;
        atomicMin(&rowMinU[col], mapf(cn));
        atomicMax(&rowMaxU[col], mapf(cx));
      }
    }
  }

  #pragma unroll
  for (int off=32; off; off>>=1){
    pos  += __shfl_xor(pos, off);
    neg  += __shfl_xor(neg, off);
    semi += __shfl_xor(semi, off);
    diag += __shfl_xor(diag, off);
  }
  if (lane == 0){
    float fac = isDiag ? 1.f : 2.f;
    pairPart[t*4+0] = pos*fac;
    pairPart[t*4+1] = neg*fac;
    pairPart[t*4+2] = semi*fac;
    pairPart[t*4+3] = diag;
  }
}

// ============ k_final: 1024 threads; histogram + reductions + combine ======
__global__ __launch_bounds__(1024) void k_final(const int* __restrict__ targets,
    const int* __restrict__ epoch_p, int B, int nprep, int nblk,
    const float* __restrict__ pairPart, const float* __restrict__ psum,
    const unsigned* rowMinU, const unsigned* rowMaxU, float* out){
  int tid = threadIdx.x, wave = tid>>6, lane = tid&63;
  __shared__ float redf[16][8];
  __shared__ int   redi[16][4];
  __shared__ float tot6[6];
  __shared__ int   cns[3];
  __shared__ float ptot[4];

  // ---- 1) histogram targets (int4 loads) ----
  {
    int c0=0,c1=0,c2=0;
    for (int i4 = tid; i4 < B/4; i4 += 1024){
      int4 tv = ((const int4*)targets)[i4];
      c0 += (tv.x==0)+(tv.y==0)+(tv.z==0)+(tv.w==0);
      c1 += (tv.x==1)+(tv.y==1)+(tv.z==1)+(tv.w==1);
      c2 += (tv.x==2)+(tv.y==2)+(tv.z==2)+(tv.w==2);
    }
    #pragma unroll
    for (int off=32; off; off>>=1){
      c0+=__shfl_xor(c0,off); c1+=__shfl_xor(c1,off); c2+=__shfl_xor(c2,off);
    }
    if (lane==0){ redi[wave][0]=c0; redi[wave][1]=c1; redi[wave][2]=c2; }
  }
  // ---- 2) per-sample partials ----
  {
    float v0=0,v1=0,v2=0,v3=0,v4=0,v5=0;
    for (int s = tid; s < nprep; s += 1024){
      float4 a = *(const float4*)(psum + s*8);
      float4 b = *(const float4*)(psum + s*8 + 4);
      v0+=a.x; v1+=a.y; v2+=a.z; v3+=a.w; v4+=b.x; v5+=b.y;
    }
    #pragma unroll
    for (int off=32; off; off>>=1){
      v0+=__shfl_xor(v0,off); v1+=__shfl_xor(v1,off); v2+=__shfl_xor(v2,off);
      v3+=__shfl_xor(v3,off); v4+=__shfl_xor(v4,off); v5+=__shfl_xor(v5,off);
    }
    if (lane==0){
      redf[wave][0]=v0; redf[wave][1]=v1; redf[wave][2]=v2;
      redf[wave][3]=v3; redf[wave][4]=v4; redf[wave][5]=v5;
    }
  }
  __syncthreads();
  if (tid == 0){
    int c0=0,c1=0,c2=0;
    float v[6]={0,0,0,0,0,0};
    for (int w2=0; w2<16; w2++){
      c0+=redi[w2][0]; c1+=redi[w2][1]; c2+=redi[w2][2];
      for (int j=0;j<6;j++) v[j]+=redf[w2][j];
    }
    cns[0]=c0; cns[1]=c1; cns[2]=c2;
    for (int j=0;j<6;j++) tot6[j]=v[j];
  }
  __syncthreads();

  // ---- 3) pair partials ----
  {
    float p=0,n=0,s2=0,d=0;
    for (int s = tid; s < nblk; s += 1024){
      float4 a = *(const float4*)(pairPart + s*4);
      p+=a.x; n+=a.y; s2+=a.z; d+=a.w;
    }
    #pragma unroll
    for (int off=32; off; off>>=1){
      p+=__shfl_xor(p,off); n+=__shfl_xor(n,off);
      s2+=__shfl_xor(s2,off); d+=__shfl_xor(d,off);
    }
    if (lane==0){ redf[wave][0]=p; redf[wave][1]=n; redf[wave][2]=s2; redf[wave][3]=d; }
  }
  __syncthreads();
  if (tid == 0){
    float a=0,b=0,c=0,e=0;
    for (int w2=0; w2<16; w2++){ a+=redf[w2][0]; b+=redf[w2][1]; c+=redf[w2][2]; e+=redf[w2][3]; }
    ptot[0]=a; ptot[1]=b; ptot[2]=c; ptot[3]=e;
  }
  __syncthreads();

  int n0=cns[0], n1=cns[1], n2=cns[2];

  // ---- 4) triplet ----
  float tsum = 0.f, tcnt = 0.f;
  for (int i = tid; i < B; i += 1024){
    int t = targets[i];
    int nt = (t==0)?n0:((t==1)?n1:n2);
    if (nt - 1 > 0 && B - nt > 0){
      float mn = unmapf(rowMinU[i]);
      float mx = unmapf(rowMaxU[i]);
      float hp = sqrtf(fmaxf(2.f - 2.f*mn, 0.f));
      float hn = sqrtf(fmaxf(2.f - 2.f*mx, 0.f));
      float margin = 1.5f * ((t==1) ? 2.5f : 1.f);
      float tl = fmaxf(hp - hn + margin, 0.f);
      tsum += tl; tcnt += 1.f;
    }
  }
  #pragma unroll
  for (int off=32; off; off>>=1){ tsum += __shfl_xor(tsum, off); tcnt += __shfl_xor(tcnt, off); }
  if (lane==0){ redf[wave][6]=tsum; redf[wave][7]=tcnt; }
  __syncthreads();

  if (tid==0){
    float ts=0, tn=0;
    for (int w2=0; w2<16; w2++){ ts+=redf[w2][6]; tn+=redf[w2][7]; }
    float triplet = (tn > 0.f) ? ts / fmaxf(tn, 1.f) : 0.f;
    float pos=ptot[0], neg=ptot[1], semi=ptot[2], diag=ptot[3];
    float Bf = (float)B;
    float focal = tot6[0] / Bf;
    float ce = tot6[1] / tot6[2];
    float boundary = tot6[3] / (Bf + 1e-8f);
    float contrastive = (pos + neg + 4.f*semi) / (Bf*Bf + 1e-8f);
    long long npl = ((long long)n0*(n0-1) + (long long)n1*(n1-1) + (long long)n2*(n2-1))/2;
    float qsum = (pos - diag) * 0.5f;
    float q = qsum / (float)(npl > 0 ? npl : 1);
    if (n2 > 0) q *= (1.f + 2.5f * ((float)n2 / Bf));
    float quality = (npl > 0) ? q : 0.f;
    int ep = epoch_p[0];
    float er = (float)ep / 25.f;
    float ann = fminf(1.f, er*er);
    float evidential = tot6[4]/Bf + ann*0.2f*tot6[5]/Bf;
    float total = 0.4f*focal + 0.3f*ce + 0.15f*boundary
                + 0.1f*contrastive + 0.1f*triplet + 0.1f*quality + 0.1f*evidential;
    out[0] = total;
  }
}

extern "C" void kernel_launch(void* const* d_in, const int* in_sizes, int n_in,
                              void* d_out, int out_size, void* d_ws, size_t ws_size,
                              hipStream_t stream){
  const float* logits   = (const float*)d_in[0];
  const int*   targets  = (const int*)d_in[1];
  const float* features = (const float*)d_in[2];
  const float* alpha    = (const float*)d_in[3];
  const int*   epoch    = (const int*)d_in[4];
  const float* fa       = (const float*)d_in[5];
  const float* cw       = (const float*)d_in[6];
  int B = in_sizes[1];
  int D = in_sizes[2] / B;
  int nprep = B/4;                 // k_prep blocks == psum slots
  int T  = B / 64;
  int nblk = T*(T+1)/2;            // triangular: by <= bx  (2080 @ B=4096)

  char* ws = (char*)d_ws;
  float*    psum     = (float*)(ws);                          // nprep*8 f32 (32KB)
  float*    pairPart = (float*)(ws + 65536);                  // nblk*4 f32 (~33KB)
  unsigned* rowMinU  = (unsigned*)(ws + 131072);              // B u32
  unsigned* rowMaxU  = (unsigned*)(ws + 131072 + (size_t)B*4);
  __bf16*   fb2      = (__bf16*)(ws + 131072 + (size_t)B*8);  // B*D bf16 tiled

  k_prep <<<nprep, 256, 0, stream>>>(features, fb2, logits, targets, alpha, fa, cw,
                                     B, D, psum, rowMinU, rowMaxU);
  k_pairs<<<nblk, 64, 0, stream>>>(fb2, targets, B, D, nblk, pairPart,
                                   rowMinU, rowMaxU);
  k_final<<<1, 1024, 0, stream>>>(targets, epoch, B, nprep, nblk, pairPart, psum,
                                  rowMinU, rowMaxU, (float*)d_out);
}

// Round 8
// 120.429 us; speedup vs baseline: 1.1424x; 1.0239x over previous
//
#include <hip/hip_runtime.h>
#include <hip/hip_bf16.h>
#include <cstdint>

typedef __attribute__((ext_vector_type(8))) __bf16 bf8;
typedef __attribute__((ext_vector_type(4))) float f32x4;

#if defined(__has_builtin)
#if __has_builtin(__builtin_amdgcn_global_load_lds)
#define USE_GLL 1
#endif
#endif
#ifndef USE_GLL
#define USE_GLL 0
#endif

#if USE_GLL
// global src is a PER-LANE address; LDS dst is wave-uniform base,
// HW deposits lane i at dst + i*16B.
__device__ __forceinline__ void gll16(const __bf16* g, __bf16* l){
  __builtin_amdgcn_global_load_lds(
      (const __attribute__((address_space(1))) void*)g,
      (__attribute__((address_space(3))) void*)l, 16, 0, 0);
}
#endif

// order-preserving float<->uint maps (for atomicMin/Max on sim values)
__device__ __forceinline__ unsigned mapf(float x){
  unsigned u = __float_as_uint(x);
  return (u & 0x80000000u) ? ~u : (u | 0x80000000u);
}
__device__ __forceinline__ float unmapf(unsigned u){
  return __uint_as_float((u & 0x80000000u) ? (u & 0x7FFFFFFFu) : ~u);
}

__device__ float digammaf_(float x){
  float r = 0.f;
  while (x < 6.f){ r -= 1.f/x; x += 1.f; }
  float inv = 1.f/x, inv2 = inv*inv;
  r += logf(x) - 0.5f*inv
     - inv2*(0.08333333333f - inv2*(0.008333333333f - inv2*0.003968253968f));
  return r;
}

// ============ k_prep: normalize -> TILED bf16 (fb2, 128-row panels) ========
// fb2 layout: panel p=row/128, chunk c=k/32; each chunk is 8KB CONTIGUOUS:
// elem (r=row%128, kk=k%32) at (p*NCH+c)*4096 + r*32 + cb'*8 + kk%8,
// cb' = (kk/8) ^ ((r>>1)&3)  (bank swizzle pre-baked, same as round 0).
__global__ __launch_bounds__(256) void k_prep(const float* __restrict__ feat,
    __bf16* __restrict__ fb2,
    const float* __restrict__ logits, const int* __restrict__ targets,
    const float* __restrict__ alpha,  const float* __restrict__ fa,
    const float* __restrict__ cw, int B, int D,
    float* __restrict__ psum, unsigned* rowMinU, unsigned* rowMaxU){
  int bid = blockIdx.x, tid = threadIdx.x;
  int wave = tid >> 6, lane = tid & 63;

  int row = bid*4 + wave;                       // grid = B/4, always < B
  // ---- normalize one row per wave ----
  const float* src = feat + (size_t)row*D;
  float ss = 0.f;
  for (int c = lane*4; c < D; c += 64*4){
    float4 v = *(const float4*)(src + c);
    ss += v.x*v.x + v.y*v.y + v.z*v.z + v.w*v.w;
  }
  #pragma unroll
  for (int off=32; off; off>>=1) ss += __shfl_xor(ss, off);
  float inv = 1.f / fmaxf(sqrtf(ss), 1e-12f);

  int p = row >> 7, r = row & 127;
  int rsw = (r >> 1) & 3;
  int NCH = D >> 5;
  for (int c = lane*8; c < D; c += 64*8){
    float4 v0 = *(const float4*)(src + c);
    float4 v1 = *(const float4*)(src + c + 4);
    bf8 o;
    o[0]=(__bf16)(v0.x*inv); o[1]=(__bf16)(v0.y*inv);
    o[2]=(__bf16)(v0.z*inv); o[3]=(__bf16)(v0.w*inv);
    o[4]=(__bf16)(v1.x*inv); o[5]=(__bf16)(v1.y*inv);
    o[6]=(__bf16)(v1.z*inv); o[7]=(__bf16)(v1.w*inv);
    int cc = c >> 5;                  // chunk
    int cb = (c >> 3) & 3;            // 8-elem group within chunk
    size_t off = (size_t)(p*NCH + cc)*4096 + r*32 + ((cb ^ rsw)*8);
    *(bf8*)(fb2 + off) = o;
  }

  // ---- init row min/max (4 rows per block) ----
  if (tid < 4){ rowMinU[bid*4+tid] = 0xFFFFFFFFu; rowMaxU[bid*4+tid] = 0u; }

  // ---- per-sample losses: wave 0 only, lanes 0..3 take the 4 samples ----
  // (validated rounds 1-7; psum bit-identical to round-0's redundant version)
  if (wave == 0){
    float r0=0.f,r1=0.f,r2=0.f,r3=0.f,r4=0.f,r5=0.f;
    if (lane < 4){
      int i = bid*4 + lane;
      float l0=logits[3*i], l1=logits[3*i+1], l2=logits[3*i+2];
      int t = targets[i];
      float m = fmaxf(l0, fmaxf(l1,l2));
      float e0=expf(l0-m), e1=expf(l1-m), e2=expf(l2-m);
      float se = e0+e1+e2;
      float lse = m + logf(se);
      float lp0=l0-lse, lp1=l1-lse, lp2=l2-lse;
      float lpt = (t==0)?lp0:((t==1)?lp1:lp2);
      float nll = -lpt;
      float ce_ls = 0.9f*nll + 0.1f*(-(lp0+lp1+lp2)*(1.f/3.f));
      float pt = expf(-ce_ls);
      float om = 1.f - pt;
      float focal_i = fa[t]*om*om*ce_ls;
      float w = cw[t];
      float ce_n = w*nll, ce_d = w;
      float p0=e0/se, p1=e1/se, p2=e2/se;
      float bnd;
      if (t==0)      bnd = p1 + 0.6f*p2;
      else if (t==2) bnd = p1 + 0.4f*p0;
      else           bnd = 4.5f*(1.f - p1 + 0.3f*(p0+p2));
      float a0=alpha[3*i], a1=alpha[3*i+1], a2=alpha[3*i+2];
      float S = a0+a1+a2 + 1e-8f;
      float at_ = (t==0)?a0:((t==1)?a1:a2);
      float lik = digammaf_(S) - digammaf_(at_ + 1e-8f);
      float b0 = (t==0)?1.f:a0, b1 = (t==1)?1.f:a1, b2 = (t==2)?1.f:a2;
      float ats = b0+b1+b2 + 1e-8f;
      float psa = digammaf_(ats + 1e-8f);
      float kl = lgammaf(ats)
         - (lgammaf(b0+1e-8f)+lgammaf(b1+1e-8f)+lgammaf(b2+1e-8f))
         + (b0-1.f)*(digammaf_(b0+1e-8f)-psa)
         + (b1-1.f)*(digammaf_(b1+1e-8f)-psa)
         + (b2-1.f)*(digammaf_(b2+1e-8f)-psa);
      r0=focal_i; r1=ce_n; r2=ce_d; r3=bnd; r4=lik; r5=kl;
    }
    float s0 = ((__shfl(r0,0)+__shfl(r0,1))+__shfl(r0,2))+__shfl(r0,3);
    float s1 = ((__shfl(r1,0)+__shfl(r1,1))+__shfl(r1,2))+__shfl(r1,3);
    float s2 = ((__shfl(r2,0)+__shfl(r2,1))+__shfl(r2,2))+__shfl(r2,3);
    float s3 = ((__shfl(r3,0)+__shfl(r3,1))+__shfl(r3,2))+__shfl(r3,3);
    float s4 = ((__shfl(r4,0)+__shfl(r4,1))+__shfl(r4,2))+__shfl(r4,3);
    float s5 = ((__shfl(r5,0)+__shfl(r5,1))+__shfl(r5,2))+__shfl(r5,3);
    if (lane == 0){
      psum[bid*8+0]=s0; psum[bid*8+1]=s1; psum[bid*8+2]=s2;
      psum[bid*8+3]=s3; psum[bid*8+4]=s4; psum[bid*8+5]=s5;
    }
  }
}

// ============ k_pairs: 128x128 blocks, 4 waves, m97 barrier pipeline ========
// Traffic cut 4x vs round-0 (532->135 MB): 528 triangular 128-blocks, each
// stages A/B panels ONCE; wave w computes quadrant (wr=w>>1, wc=w&1) with the
// round-0 fragment reads / MFMA order / epilogue VERBATIM (sims bit-identical).
// Sync = standard STAGE -> __syncthreads -> COMPUTE double-buffer: the
// barrier's vmcnt(0)+lgkmcnt(0) drain guarantees correctness (no reliance on
// fine waitcnt tracking — round-6's failure mode).
// Diag blocks (by==bx): all 4 quadrants computed, fac=1, no col atomics
// (the transposed quadrant covers them). Off-diag: fac=2 + col atomics.
__global__ __launch_bounds__(256) void k_pairs(const __bf16* __restrict__ fb2,
    const int* __restrict__ targets, int B, int D,
    float* __restrict__ pairPart, unsigned* rowMinU, unsigned* rowMaxU){
  __shared__ __bf16 sA[2][4096];
  __shared__ __bf16 sB[2][4096];

  int t = blockIdx.x;
  // decode triangular tile index -> (by, bx), by <= bx
  int bx = (int)((sqrtf(8.f*(float)t + 1.f) - 1.f)*0.5f);
  while ((bx+1)*(bx+2)/2 <= t) bx++;
  while (bx*(bx+1)/2 > t) bx--;
  int by = t - bx*(bx+1)/2;
  bool isDiag = (by == bx);

  int tid = threadIdx.x;
  int wave = tid >> 6, lane = tid & 63;
  int wr = wave >> 1, wc = wave & 1;
  int quad = lane >> 4, l16 = lane & 15;
  int NCH = D >> 5;                                 // 16 chunks per panel

  int rowBase = by*128 + wr*64, colBase = bx*128 + wc*64;

  // staging pointers: wave w stages slices [w*1024, w*1024+1024) of each 4096-
  // elem chunk (2 gll16 of 512 elems each); LDS copy is LINEAR vs global.
  int woff = wave*1024;
  const __bf16* srcA = fb2 + (size_t)by*NCH*4096 + woff + lane*8;
  const __bf16* srcB = fb2 + (size_t)bx*NCH*4096 + woff + lane*8;
  const __bf16* sB0  = isDiag ? &sA[0][0] : &sB[0][0];

  // fragment LDS offsets (elements), inverse swizzle (round-0 formula,
  // R now spans the wave's 64-row half of the 128-row panel)
  int offA[4], offB[4];
  #pragma unroll
  for (int mi=0; mi<4; mi++){
    int RA = wr*64 + mi*16 + l16;
    offA[mi] = RA*32 + ((quad ^ ((RA>>1)&3))*8);
    int RB = wc*64 + mi*16 + l16;
    offB[mi] = RB*32 + ((quad ^ ((RB>>1)&3))*8);
  }

  f32x4 C[4][4] = {};

#if USE_GLL
  #define STAGE(buf, it) do{ \
    gll16(srcA + (it)*4096 + 0*512, &sA[buf][woff + 0*512]); \
    gll16(srcA + (it)*4096 + 1*512, &sA[buf][woff + 1*512]); \
    if (!isDiag){ \
      gll16(srcB + (it)*4096 + 0*512, &sB[buf][woff + 0*512]); \
      gll16(srcB + (it)*4096 + 1*512, &sB[buf][woff + 1*512]); \
    } \
  }while(0)
#else
  #define STAGE(buf, it) do{ \
    _Pragma("unroll") \
    for (int j=0; j<2; j++) \
      *(bf8*)&sA[buf][woff + j*512 + lane*8] = *(const bf8*)(srcA + (it)*4096 + j*512); \
    if (!isDiag){ \
      _Pragma("unroll") \
      for (int j=0; j<2; j++) \
        *(bf8*)&sB[buf][woff + j*512 + lane*8] = *(const bf8*)(srcB + (it)*4096 + j*512); \
    } \
  }while(0)
#endif

  #define COMPUTE(buf) do{ \
    bf8 aF[4], bF[4]; \
    _Pragma("unroll") \
    for (int mi=0; mi<4; mi++) aF[mi] = *(const bf8*)(&sA[0][0] + (buf)*4096 + offA[mi]); \
    _Pragma("unroll") \
    for (int ni=0; ni<4; ni++) bF[ni] = *(const bf8*)(sB0 + (buf)*4096 + offB[ni]); \
    _Pragma("unroll") \
    for (int mi=0; mi<4; mi++) \
      _Pragma("unroll") \
      for (int ni=0; ni<4; ni++) \
        C[mi][ni] = __builtin_amdgcn_mfma_f32_16x16x32_bf16(aF[mi], bF[ni], C[mi][ni], 0,0,0); \
  }while(0)

  STAGE(0, 0);
  __syncthreads();                       // buf0 complete (vmcnt drained)
  for (int it=0; it<NCH; it+=2){
    STAGE(1, it+1);                      // DMA flies under COMPUTE(0)
    COMPUTE(0);
    __syncthreads();                     // buf1 ready; buf0 reads retired
    if (it+2 < NCH) STAGE(0, it+2);
    COMPUTE(1);
    __syncthreads();                     // buf0 ready; buf1 reads retired
  }
  #undef STAGE
  #undef COMPUTE

  // ---- fused epilogue (round-0 verbatim per wave/quadrant) ----
  int tcol[4];
  #pragma unroll
  for (int ni=0; ni<4; ni++) tcol[ni] = targets[colBase + ni*16 + l16];

  float pos=0.f, neg=0.f, semi=0.f, diag=0.f;
  float cmin[4], cmax[4];
  #pragma unroll
  for (int ni=0; ni<4; ni++){ cmin[ni]=2.f; cmax[ni]=-2.f; }

  #pragma unroll
  for (int mi=0; mi<4; mi++){
    #pragma unroll
    for (int r=0; r<4; r++){
      int rl = mi*16 + quad*4 + r;
      int row = rowBase + rl;
      int tr = targets[row];
      float vmin = 2.f, vmax = -2.f;
      #pragma unroll
      for (int ni=0; ni<4; ni++){
        int col = colBase + ni*16 + l16;
        float s = C[mi][ni][r];
        if (tr == tcol[ni]){
          float omv = 1.f - s;
          float q = omv*omv;
          pos += q;
          if (tr == 1) semi += q;
          if (row == col) diag += q;     // only on diag-block (0,0)/(1,1)
          else {
            vmin = fminf(vmin, s);
            cmin[ni] = fminf(cmin[ni], s);
          }
        } else {
          float c0 = fmaxf(s - 0.2f, 0.f);
          neg += c0*c0;
          vmax = fmaxf(vmax, s);
          cmax[ni] = fmaxf(cmax[ni], s);
        }
      }
      #pragma unroll
      for (int off=1; off<16; off<<=1){
        vmin = fminf(vmin, __shfl_xor(vmin, off));
        vmax = fmaxf(vmax, __shfl_xor(vmax, off));
      }
      if (l16 == 0){
        atomicMin(&rowMinU[row], mapf(vmin));
        atomicMax(&rowMaxU[row], mapf(vmax));
      }
    }
  }

  if (!isDiag){                          // diag blocks: transpose quadrant
    #pragma unroll                       // covers cols directly
    for (int ni=0; ni<4; ni++){
      float cn = cmin[ni], cx = cmax[ni];
      cn = fminf(cn, __shfl_xor(cn, 16)); cn = fminf(cn, __shfl_xor(cn, 32));
      cx = fmaxf(cx, __shfl_xor(cx, 16)); cx = fmaxf(cx, __shfl_xor(cx, 32));
      if (quad == 0){
        int col = colBase + ni*16 + l16;
        atomicMin(&rowMinU[col], mapf(cn));
        atomicMax(&rowMaxU[col], mapf(cx));
      }
    }
  }

  #pragma unroll
  for (int off=32; off; off>>=1){
    pos  += __shfl_xor(pos, off);
    neg  += __shfl_xor(neg, off);
    semi += __shfl_xor(semi, off);
    diag += __shfl_xor(diag, off);
  }
  if (lane == 0){
    float fac = isDiag ? 1.f : 2.f;      // diag block: every quadrant once
    float* dst = pairPart + ((size_t)t*4 + wave)*4;
    dst[0] = pos*fac; dst[1] = neg*fac; dst[2] = semi*fac; dst[3] = diag;
  }
}

// ============ k_final: 1024 threads; histogram + reductions + combine ======
__global__ __launch_bounds__(1024) void k_final(const int* __restrict__ targets,
    const int* __restrict__ epoch_p, int B, int nprep, int nblk,
    const float* __restrict__ pairPart, const float* __restrict__ psum,
    const unsigned* rowMinU, const unsigned* rowMaxU, float* out){
  int tid = threadIdx.x, wave = tid>>6, lane = tid&63;
  __shared__ float redf[16][8];
  __shared__ int   redi[16][4];
  __shared__ float tot6[6];
  __shared__ int   cns[3];
  __shared__ float ptot[4];

  // ---- 1) histogram targets (int4 loads) ----
  {
    int c0=0,c1=0,c2=0;
    for (int i4 = tid; i4 < B/4; i4 += 1024){
      int4 tv = ((const int4*)targets)[i4];
      c0 += (tv.x==0)+(tv.y==0)+(tv.z==0)+(tv.w==0);
      c1 += (tv.x==1)+(tv.y==1)+(tv.z==1)+(tv.w==1);
      c2 += (tv.x==2)+(tv.y==2)+(tv.z==2)+(tv.w==2);
    }
    #pragma unroll
    for (int off=32; off; off>>=1){
      c0+=__shfl_xor(c0,off); c1+=__shfl_xor(c1,off); c2+=__shfl_xor(c2,off);
    }
    if (lane==0){ redi[wave][0]=c0; redi[wave][1]=c1; redi[wave][2]=c2; }
  }
  // ---- 2) per-sample partials ----
  {
    float v0=0,v1=0,v2=0,v3=0,v4=0,v5=0;
    for (int s = tid; s < nprep; s += 1024){
      float4 a = *(const float4*)(psum + s*8);
      float4 b = *(const float4*)(psum + s*8 + 4);
      v0+=a.x; v1+=a.y; v2+=a.z; v3+=a.w; v4+=b.x; v5+=b.y;
    }
    #pragma unroll
    for (int off=32; off; off>>=1){
      v0+=__shfl_xor(v0,off); v1+=__shfl_xor(v1,off); v2+=__shfl_xor(v2,off);
      v3+=__shfl_xor(v3,off); v4+=__shfl_xor(v4,off); v5+=__shfl_xor(v5,off);
    }
    if (lane==0){
      redf[wave][0]=v0; redf[wave][1]=v1; redf[wave][2]=v2;
      redf[wave][3]=v3; redf[wave][4]=v4; redf[wave][5]=v5;
    }
  }
  __syncthreads();
  if (tid == 0){
    int c0=0,c1=0,c2=0;
    float v[6]={0,0,0,0,0,0};
    for (int w2=0; w2<16; w2++){
      c0+=redi[w2][0]; c1+=redi[w2][1]; c2+=redi[w2][2];
      for (int j=0;j<6;j++) v[j]+=redf[w2][j];
    }
    cns[0]=c0; cns[1]=c1; cns[2]=c2;
    for (int j=0;j<6;j++) tot6[j]=v[j];
  }
  __syncthreads();

  // ---- 3) pair partials ----
  {
    float p=0,n=0,s2=0,d=0;
    for (int s = tid; s < nblk; s += 1024){
      float4 a = *(const float4*)(pairPart + s*4);
      p+=a.x; n+=a.y; s2+=a.z; d+=a.w;
    }
    #pragma unroll
    for (int off=32; off; off>>=1){
      p+=__shfl_xor(p,off); n+=__shfl_xor(n,off);
      s2+=__shfl_xor(s2,off); d+=__shfl_xor(d,off);
    }
    if (lane==0){ redf[wave][0]=p; redf[wave][1]=n; redf[wave][2]=s2; redf[wave][3]=d; }
  }
  __syncthreads();
  if (tid == 0){
    float a=0,b=0,c=0,e=0;
    for (int w2=0; w2<16; w2++){ a+=redf[w2][0]; b+=redf[w2][1]; c+=redf[w2][2]; e+=redf[w2][3]; }
    ptot[0]=a; ptot[1]=b; ptot[2]=c; ptot[3]=e;
  }
  __syncthreads();

  int n0=cns[0], n1=cns[1], n2=cns[2];

  // ---- 4) triplet ----
  float tsum = 0.f, tcnt = 0.f;
  for (int i = tid; i < B; i += 1024){
    int t = targets[i];
    int nt = (t==0)?n0:((t==1)?n1:n2);
    if (nt - 1 > 0 && B - nt > 0){
      float mn = unmapf(rowMinU[i]);
      float mx = unmapf(rowMaxU[i]);
      float hp = sqrtf(fmaxf(2.f - 2.f*mn, 0.f));
      float hn = sqrtf(fmaxf(2.f - 2.f*mx, 0.f));
      float margin = 1.5f * ((t==1) ? 2.5f : 1.f);
      float tl = fmaxf(hp - hn + margin, 0.f);
      tsum += tl; tcnt += 1.f;
    }
  }
  #pragma unroll
  for (int off=32; off; off>>=1){ tsum += __shfl_xor(tsum, off); tcnt += __shfl_xor(tcnt, off); }
  if (lane==0){ redf[wave][6]=tsum; redf[wave][7]=tcnt; }
  __syncthreads();

  if (tid==0){
    float ts=0, tn=0;
    for (int w2=0; w2<16; w2++){ ts+=redf[w2][6]; tn+=redf[w2][7]; }
    float triplet = (tn > 0.f) ? ts / fmaxf(tn, 1.f) : 0.f;
    float pos=ptot[0], neg=ptot[1], semi=ptot[2], diag=ptot[3];
    float Bf = (float)B;
    float focal = tot6[0] / Bf;
    float ce = tot6[1] / tot6[2];
    float boundary = tot6[3] / (Bf + 1e-8f);
    float contrastive = (pos + neg + 4.f*semi) / (Bf*Bf + 1e-8f);
    long long npl = ((long long)n0*(n0-1) + (long long)n1*(n1-1) + (long long)n2*(n2-1))/2;
    float qsum = (pos - diag) * 0.5f;
    float q = qsum / (float)(npl > 0 ? npl : 1);
    if (n2 > 0) q *= (1.f + 2.5f * ((float)n2 / Bf));
    float quality = (npl > 0) ? q : 0.f;
    int ep = epoch_p[0];
    float er = (float)ep / 25.f;
    float ann = fminf(1.f, er*er);
    float evidential = tot6[4]/Bf + ann*0.2f*tot6[5]/Bf;
    float total = 0.4f*focal + 0.3f*ce + 0.15f*boundary
                + 0.1f*contrastive + 0.1f*triplet + 0.1f*quality + 0.1f*evidential;
    out[0] = total;
  }
}

extern "C" void kernel_launch(void* const* d_in, const int* in_sizes, int n_in,
                              void* d_out, int out_size, void* d_ws, size_t ws_size,
                              hipStream_t stream){
  const float* logits   = (const float*)d_in[0];
  const int*   targets  = (const int*)d_in[1];
  const float* features = (const float*)d_in[2];
  const float* alpha    = (const float*)d_in[3];
  const int*   epoch    = (const int*)d_in[4];
  const float* fa       = (const float*)d_in[5];
  const float* cw       = (const float*)d_in[6];
  int B = in_sizes[1];
  int D = in_sizes[2] / B;
  int nprep = B/4;                 // k_prep blocks == psum slots
  int T  = B / 128;                // 128-row panels (32 @ B=4096)
  int nblk = T*(T+1)/2;            // triangular 128-blocks (528 @ B=4096)
  int nslot = nblk*4;              // one pairPart slot per wave (2112)

  char* ws = (char*)d_ws;
  float*    psum     = (float*)(ws);                          // nprep*8 f32 (32KB)
  float*    pairPart = (float*)(ws + 65536);                  // nslot*4 f32 (~34KB)
  unsigned* rowMinU  = (unsigned*)(ws + 131072);              // B u32
  unsigned* rowMaxU  = (unsigned*)(ws + 131072 + (size_t)B*4);
  __bf16*   fb2      = (__bf16*)(ws + 131072 + (size_t)B*8);  // B*D bf16 tiled

  k_prep <<<nprep, 256, 0, stream>>>(features, fb2, logits, targets, alpha, fa, cw,
                                     B, D, psum, rowMinU, rowMaxU);
  k_pairs<<<nblk, 256, 0, stream>>>(fb2, targets, B, D, pairPart,
                                    rowMinU, rowMaxU);
  k_final<<<1, 1024, 0, stream>>>(targets, epoch, B, nprep, nslot, pairPart, psum,
                                  rowMinU, rowMaxU, (float*)d_out);
}